// Round 9
// baseline (809.692 us; speedup 1.0000x reference)
//
#include <hip/hip_runtime.h>

// Batched Jacobi diffusion, B=8, 128x128, iters=1000. One 1024-thread block
// per batch. Round 9 layout: each wave spans a FULL grid row-strip
// (64 lanes x 2 cols = 128 cols, 8 rows/wave, 16 waves = 128 rows).
//  - horizontal exchange: DPP wave_shr:1 / wave_shl:1 with the clamp value
//    passed as DPP `old` -> bound_ctrl handles grid-edge clamping for free
//    (no cndmask, no v_cmp). Wave boundary == grid row boundary.
//  - vertical: 2x ds_read_b64 + 2x ds_write_b64 per thread (float2 halos),
//    double-buffered, 1 barrier/iter.
//  - sPad bumps block LDS to 84 KB -> max 1 block/CU -> compiler's occupancy
//    target becomes 16 waves/CU -> 128-VGPR budget (kills the 64-VGPR cap
//    that forced register shuttling for the ~120 live floats).

#define GH 128
#define GW 128
#define NW 16      // waves per block
#define RPW 8      // rows per wave
#define NT 1024

__device__ __forceinline__ float dpp_shr1(float old_v, float src) {
    // lane l gets lane l-1's src; lane 0 (invalid) gets old_v
    return __int_as_float(__builtin_amdgcn_update_dpp(
        __float_as_int(old_v), __float_as_int(src), 0x138, 0xf, 0xf, false));
}
__device__ __forceinline__ float dpp_shl1(float old_v, float src) {
    // lane l gets lane l+1's src; lane 63 (invalid) gets old_v
    return __int_as_float(__builtin_amdgcn_update_dpp(
        __float_as_int(old_v), __float_as_int(src), 0x130, 0xf, 0xf, false));
}

__global__ void __launch_bounds__(NT)
__attribute__((amdgpu_waves_per_eu(4, 4)))
jacobi_flux_kernel(const float* __restrict__ k_all,
                   const int* __restrict__ iters_p,
                   float* __restrict__ out)
{
    __shared__ __align__(16) float2 sTop[2][NW][64];   // 16 KB
    __shared__ __align__(16) float2 sBot[2][NW][64];   // 16 KB
    __shared__ float sPad[13312];                      // 52 KB occupancy limiter

    const int b   = blockIdx.x;
    const int tid = threadIdx.x;
    const int l   = tid & 63;           // lane
    const int w   = tid >> 6;           // wave 0..15
    const int R0  = w * RPW;            // first grid row of my strip
    const int c0  = l * 2;              // first grid col of my pair
    const float* kb = k_all + b * GH * GW;
    const int iters = *iters_p;

    const int wUp = (w == 0)      ? 0      : w - 1;
    const int wDn = (w == NW - 1) ? NW - 1 : w + 1;
    const bool gTop = (w == 0);
    const bool gBot = (w == NW - 1);

    // ---- one-time: normalized face conductivities (float2 per row, 64 regs) ----
    float2 rN[RPW], rS[RPW], rW_[RPW], rE_[RPW];
    #pragma unroll
    for (int i = 0; i < RPW; ++i) {
        const int r  = R0 + i;
        const int ru = (r == 0)      ? 0      : r - 1;
        const int rd = (r == GH - 1) ? GH - 1 : r + 1;
        float v[2][4];
        #pragma unroll
        for (int jj = 0; jj < 2; ++jj) {
            const int c  = c0 + jj;
            const int cl = (c == 0)      ? 0      : c - 1;
            const int cr = (c == GW - 1) ? GW - 1 : c + 1;
            float kc = kb[r * GW + c];
            float kn = 0.5f * (kc + kb[ru * GW + c]);
            float ks = 0.5f * (kc + kb[rd * GW + c]);
            float kw = 0.5f * (kc + kb[r * GW + cl]);
            float ke = 0.5f * (kc + kb[r * GW + cr]);
            float inv = 1.0f / (kn + ks + kw + ke);
            v[jj][0] = kn * inv; v[jj][1] = ks * inv;
            v[jj][2] = kw * inv; v[jj][3] = ke * inv;
        }
        rN[i]  = make_float2(v[0][0], v[1][0]);
        rS[i]  = make_float2(v[0][1], v[1][1]);
        rW_[i] = make_float2(v[0][2], v[1][2]);
        rE_[i] = make_float2(v[0][3], v[1][3]);
    }

    // ---- state ----
    float2 A[RPW], B[RPW];
    #pragma unroll
    for (int i = 0; i < RPW; ++i)
        A[i] = (R0 + i == 0) ? make_float2(1.0f, 1.0f) : make_float2(0.0f, 0.0f);

    sTop[0][w][l] = A[0];
    sBot[0][w][l] = A[RPW - 1];
    __syncthreads();

    auto step = [&](const float2 (&src)[RPW], float2 (&dst)[RPW],
                    int rp, int wp) {
        // vertical halos (issued first; latency hides under DPP + interior FMA)
        float2 hu = sBot[rp][wUp][l];   // grid row R0-1
        float2 hd = sTop[rp][wDn][l];   // grid row R0+RPW

        // horizontal neighbors via DPP; `old` = clamp value -> edges free
        float lfv[RPW], rtv[RPW];
        #pragma unroll
        for (int i = 0; i < RPW; ++i) {
            lfv[i] = dpp_shr1(src[i].x, src[i].y);  // col c0-1 (lane l-1's .y)
            rtv[i] = dpp_shl1(src[i].y, src[i].x);  // col c0+2 (lane l+1's .x)
        }

        #pragma unroll
        for (int i = 0; i < RPW; ++i) {
            float upx = (i == 0)       ? hu.x : src[i - 1].x;
            float upy = (i == 0)       ? hu.y : src[i - 1].y;
            float dnx = (i == RPW - 1) ? hd.x : src[i + 1].x;
            float dny = (i == RPW - 1) ? hd.y : src[i + 1].y;
            dst[i].x = fmaf(rN[i].x, upx,
                       fmaf(rS[i].x, dnx,
                       fmaf(rW_[i].x, lfv[i], rE_[i].x * src[i].y)));
            dst[i].y = fmaf(rN[i].y, upy,
                       fmaf(rS[i].y, dny,
                       fmaf(rW_[i].y, src[i].x, rE_[i].y * rtv[i])));
        }
        if (gTop) dst[0]       = make_float2(1.0f, 1.0f);   // Dirichlet row 0
        if (gBot) dst[RPW - 1] = make_float2(0.0f, 0.0f);   // Dirichlet row 127

        sTop[wp][w][l] = dst[0];
        sBot[wp][w][l] = dst[RPW - 1];
        __syncthreads();
    };

    const int nPairs = iters >> 1;
    for (int it = 0; it < nPairs; ++it) {
        step(A, B, 0, 1);
        step(B, A, 1, 0);
    }
    if (iters & 1) {
        step(A, B, 0, 1);
        #pragma unroll
        for (int i = 0; i < RPW; ++i) A[i] = B[i];
    }

    // ---- flux at row 64: wave 8 holds rows 64..71 (A[0]=r64, A[1]=r65) ----
    if (w == 8) {
        float p0 = kb[64 * GW + c0]     * (A[1].x - A[0].x);
        float p1 = kb[64 * GW + c0 + 1] * (A[1].y - A[0].y);
        sPad[l] = p0 + p1;               // also keeps sPad referenced
    }
    __syncthreads();
    if (tid == 0) {
        float s = 0.0f;
        #pragma unroll
        for (int i = 0; i < 64; ++i) s += sPad[i];
        out[b] = -s;
    }
}

extern "C" void kernel_launch(void* const* d_in, const int* in_sizes, int n_in,
                              void* d_out, int out_size, void* d_ws, size_t ws_size,
                              hipStream_t stream)
{
    const float* k     = (const float*)d_in[0];
    const int*   iters = (const int*)d_in[1];
    float*       out   = (float*)d_out;
    jacobi_flux_kernel<<<dim3(8), dim3(NT), 0, stream>>>(k, iters, out);
}